// Round 1
// baseline (1364.105 us; speedup 1.0000x reference)
//
#include <hip/hip_runtime.h>
#include <math.h>

#define DIM 32
#define NGRAPHS 1024

// ---------------- degree ----------------
__global__ void deg_kernel(const int* __restrict__ col, const float* __restrict__ w,
                           float* __restrict__ deg, int E) {
    int e = blockIdx.x * blockDim.x + threadIdx.x;
    if (e < E) atomicAdd(&deg[col[e]], w[e]);
}

__global__ void dinv_kernel(const float* __restrict__ deg, float* __restrict__ dinv, int N) {
    int n = blockIdx.x * blockDim.x + threadIdx.x;
    if (n < N) dinv[n] = rsqrtf(deg[n] + 1.0f);
}

// ---------------- pre-MLP (2 layers fused), thread per (n,d) ----------------
__global__ void premlp_kernel(const float* __restrict__ x,
                              const float* __restrict__ W0, const float* __restrict__ b0,
                              const float* __restrict__ W1, const float* __restrict__ b1,
                              float* __restrict__ h, int N) {
    int tid = blockIdx.x * blockDim.x + threadIdx.x;
    if (tid >= N * DIM) return;
    int n = tid >> 5, d = tid & 31;
    float xv = x[n];
    float acc = b1[d];
#pragma unroll
    for (int k = 0; k < DIM; k++) {
        float h0 = fmaxf(xv * W0[k] + b0[k], 0.0f);
        acc += h0 * W1[k * DIM + d];
    }
    h[tid] = fmaxf(acc, 0.0f);
}

// ---------------- xw = h @ W ; agg init = xw*dinv^2 + b ----------------
template <bool RELU_IN>
__global__ void xw_kernel(const float* __restrict__ hin,
                          const float* __restrict__ W, const float* __restrict__ b,
                          const float* __restrict__ dinv,
                          float* __restrict__ xw, float* __restrict__ agg, int N) {
    int tid = blockIdx.x * blockDim.x + threadIdx.x;
    if (tid >= N * DIM) return;
    int n = tid >> 5, d = tid & 31;
    const float* hr = hin + n * DIM;
    float acc = 0.0f;
#pragma unroll
    for (int k = 0; k < DIM; k++) {
        float hv = hr[k];
        if (RELU_IN) hv = fmaxf(hv, 0.0f);
        acc += hv * W[k * DIM + d];
    }
    xw[tid] = acc;
    float di = dinv[n];
    agg[tid] = acc * di * di + b[d];
}

// ---------------- edge scatter: agg[col] += dinv[row]*w*dinv[col] * xw[row] ----------------
__global__ void scatter_kernel(const int* __restrict__ row, const int* __restrict__ col,
                               const float* __restrict__ w, const float* __restrict__ dinv,
                               const float* __restrict__ xw, float* __restrict__ agg, int E) {
    int tid = blockIdx.x * blockDim.x + threadIdx.x;
    if (tid >= E * DIM) return;  // E*32 = 81.92M < 2^31
    int e = tid >> 5, d = tid & 31;
    int r = row[e], c = col[e];
    float coeff = dinv[r] * w[e] * dinv[c];
    atomicAdd(&agg[c * DIM + d], coeff * xw[r * DIM + d]);
}

// ---------------- mean pool (accumulate) ----------------
__global__ void pool_kernel(const float* __restrict__ agg, const int* __restrict__ batch,
                            float* __restrict__ sums, float* __restrict__ cnt, int N) {
    int tid = blockIdx.x * blockDim.x + threadIdx.x;
    if (tid >= N * DIM) return;
    int n = tid >> 5, d = tid & 31;
    int g = batch[n];
    atomicAdd(&sums[g * DIM + d], fmaxf(agg[tid], 0.0f));
    if (d == 0) atomicAdd(&cnt[g], 1.0f);
}

// ---------------- post-MLP: relu(g@W0+b0) @ W1 + b1 -> sigmoid ----------------
__global__ void postmlp_kernel(const float* __restrict__ sums, const float* __restrict__ cnt,
                               const float* __restrict__ W0, const float* __restrict__ b0,
                               const float* __restrict__ W1, const float* __restrict__ b1,
                               float* __restrict__ out, int G) {
    int g = blockIdx.x * blockDim.x + threadIdx.x;
    if (g >= G) return;
    float c = fmaxf(cnt[g], 1.0f);
    float inv = 1.0f / c;
    float gv[DIM];
#pragma unroll
    for (int k = 0; k < DIM; k++) gv[k] = sums[g * DIM + k] * inv;
    float acc = b1[0];
#pragma unroll
    for (int j = 0; j < DIM; j++) {
        float p = b0[j];
#pragma unroll
        for (int k = 0; k < DIM; k++) p += gv[k] * W0[k * DIM + j];
        p = fmaxf(p, 0.0f);
        acc += p * W1[j];
    }
    out[g] = 1.0f / (1.0f + expf(-acc));
}

extern "C" void kernel_launch(void* const* d_in, const int* in_sizes, int n_in,
                              void* d_out, int out_size, void* d_ws, size_t ws_size,
                              hipStream_t stream) {
    const float* x   = (const float*)d_in[0];
    const int*   ei  = (const int*)d_in[1];
    const float* ew  = (const float*)d_in[2];
    const int*   bat = (const int*)d_in[3];
    const float* Wpre0 = (const float*)d_in[4];
    const float* bpre0 = (const float*)d_in[5];
    const float* Wpre1 = (const float*)d_in[6];
    const float* bpre1 = (const float*)d_in[7];
    const float* Wg[3]  = {(const float*)d_in[8],  (const float*)d_in[10], (const float*)d_in[12]};
    const float* bg[3]  = {(const float*)d_in[9],  (const float*)d_in[11], (const float*)d_in[13]};
    const float* Wpost0 = (const float*)d_in[14];
    const float* bpost0 = (const float*)d_in[15];
    const float* Wpost1 = (const float*)d_in[16];
    const float* bpost1 = (const float*)d_in[17];
    float* out = (float*)d_out;

    const int N = in_sizes[0];       // 160000
    const int E = in_sizes[2];       // 2560000
    const int G = out_size;          // 1024

    const int* row = ei;
    const int* col = ei + E;

    // workspace layout (floats)
    float* ws = (float*)d_ws;
    size_t nd = (size_t)N * DIM;
    float* bufA = ws;
    float* bufB = bufA + nd;
    float* bufC = bufB + nd;
    float* dinv = bufC + nd;
    float* deg  = dinv + N;
    float* sums = deg + N;           // G*DIM
    float* cnt  = sums + (size_t)G * DIM;
    // zero region: deg .. cnt end (deg N + sums G*DIM + cnt G)
    hipMemsetAsync(deg, 0, sizeof(float) * ((size_t)N + (size_t)G * DIM + G), stream);

    const int B = 256;
    // degrees
    deg_kernel<<<(E + B - 1) / B, B, 0, stream>>>(col, ew, deg, E);
    dinv_kernel<<<(N + B - 1) / B, B, 0, stream>>>(deg, dinv, N);

    // pre-MLP -> bufA
    int ndThreads = N * DIM;
    premlp_kernel<<<(ndThreads + B - 1) / B, B, 0, stream>>>(x, Wpre0, bpre0, Wpre1, bpre1, bufA, N);

    // layer rotation: (in, xw, agg) = L0:(A,B,C) L1:(C,A,B) L2:(B,C,A)
    float* bin[3]  = {bufA, bufC, bufB};
    float* bxw[3]  = {bufB, bufA, bufC};
    float* bagg[3] = {bufC, bufB, bufA};

    int edThreads = E * DIM;
    for (int l = 0; l < 3; l++) {
        if (l == 0)
            xw_kernel<false><<<(ndThreads + B - 1) / B, B, 0, stream>>>(bin[l], Wg[l], bg[l], dinv, bxw[l], bagg[l], N);
        else
            xw_kernel<true><<<(ndThreads + B - 1) / B, B, 0, stream>>>(bin[l], Wg[l], bg[l], dinv, bxw[l], bagg[l], N);
        scatter_kernel<<<(edThreads + B - 1) / B, B, 0, stream>>>(row, col, ew, dinv, bxw[l], bagg[l], E);
    }

    // pool (relu fused) from bagg[2] == bufA
    pool_kernel<<<(ndThreads + B - 1) / B, B, 0, stream>>>(bagg[2], bat, sums, cnt, N);

    // post-MLP
    postmlp_kernel<<<(G + B - 1) / B, B, 0, stream>>>(sums, cnt, Wpost0, bpost0, Wpost1, bpost1, out, G);
}

// Round 2
// 1270.391 us; speedup vs baseline: 1.0738x; 1.0738x over previous
//
#include <hip/hip_runtime.h>
#include <math.h>

#define DIM 32

// ---------------- degree (weighted) + in-degree count ----------------
__global__ void deg_cnt_kernel(const int* __restrict__ col, const float* __restrict__ w,
                               float* __restrict__ deg, int* __restrict__ cnt, int E) {
    int e = blockIdx.x * blockDim.x + threadIdx.x;
    if (e < E) {
        int c = col[e];
        atomicAdd(&deg[c], w[e]);
        atomicAdd(&cnt[c], 1);
    }
}

// dinv = rsqrt(deg+1), in place
__global__ void dinv_kernel(float* __restrict__ deg, int N) {
    int n = blockIdx.x * blockDim.x + threadIdx.x;
    if (n < N) deg[n] = rsqrtf(deg[n] + 1.0f);
}

// ---------------- scan: per-block exclusive scan of cnt -> ptr, block totals -> bsum ----------------
__global__ void scan_block_kernel(const int* __restrict__ cnt, int* __restrict__ ptr,
                                  int* __restrict__ bsum, int N) {
    __shared__ int s[256];
    int i = blockIdx.x * 256 + threadIdx.x;
    int v = (i < N) ? cnt[i] : 0;
    s[threadIdx.x] = v;
    __syncthreads();
#pragma unroll
    for (int off = 1; off < 256; off <<= 1) {
        int t = (threadIdx.x >= off) ? s[threadIdx.x - off] : 0;
        __syncthreads();
        s[threadIdx.x] += t;
        __syncthreads();
    }
    if (i < N) ptr[i] = s[threadIdx.x] - v;  // exclusive
    if (threadIdx.x == 255) bsum[blockIdx.x] = s[255];
}

// serial scan of block totals (nb=625, trivial)
__global__ void scan_tops_kernel(int* __restrict__ bsum, int* __restrict__ ptr, int nb, int N) {
    if (blockIdx.x == 0 && threadIdx.x == 0) {
        int run = 0;
        for (int b = 0; b < nb; b++) { int t = bsum[b]; bsum[b] = run; run += t; }
        ptr[N] = run;  // == E
    }
}

// add block offsets; also init cursor (reuses cnt buffer)
__global__ void scan_add_kernel(int* __restrict__ ptr, const int* __restrict__ bsum,
                                int* __restrict__ cursor, int N) {
    int i = blockIdx.x * blockDim.x + threadIdx.x;
    if (i < N) {
        int p = ptr[i] + bsum[i >> 8];
        ptr[i] = p;
        cursor[i] = p;
    }
}

// ---------------- counting-sort edges by col; precompute norm once ----------------
__global__ void sort_kernel(const int* __restrict__ row, const int* __restrict__ col,
                            const float* __restrict__ w, const float* __restrict__ dinv,
                            int* __restrict__ cursor, float2* __restrict__ edat, int E) {
    int e = blockIdx.x * blockDim.x + threadIdx.x;
    if (e >= E) return;
    int r = row[e], c = col[e];
    float nm = dinv[r] * w[e] * dinv[c];
    int pos = atomicAdd(&cursor[c], 1);
    edat[pos] = make_float2(__int_as_float(r), nm);
}

// ---------------- pre-MLP (2 layers fused), thread per (n,d) ----------------
__global__ void premlp_kernel(const float* __restrict__ x,
                              const float* __restrict__ W0, const float* __restrict__ b0,
                              const float* __restrict__ W1, const float* __restrict__ b1,
                              float* __restrict__ h, int N) {
    int tid = blockIdx.x * blockDim.x + threadIdx.x;
    if (tid >= N * DIM) return;
    int n = tid >> 5, d = tid & 31;
    float xv = x[n];
    float acc = b1[d];
#pragma unroll
    for (int k = 0; k < DIM; k++) {
        float h0 = fmaxf(xv * W0[k] + b0[k], 0.0f);
        acc += h0 * W1[k * DIM + d];
    }
    h[tid] = fmaxf(acc, 0.0f);
}

// ---------------- xw = (relu?)h @ W ----------------
template <bool RELU_IN>
__global__ void xw_kernel(const float* __restrict__ hin, const float* __restrict__ W,
                          float* __restrict__ xw, int N) {
    int tid = blockIdx.x * blockDim.x + threadIdx.x;
    if (tid >= N * DIM) return;
    int n = tid >> 5, d = tid & 31;
    const float* hr = hin + n * DIM;
    float acc = 0.0f;
#pragma unroll
    for (int k = 0; k < DIM; k++) {
        float hv = hr[k];
        if (RELU_IN) hv = fmaxf(hv, 0.0f);
        acc += hv * W[k * DIM + d];
    }
    xw[tid] = acc;
}

// ---------------- CSR gather: out[n] = b + xw[n]*dinv^2 + sum_e norm*xw[row] ----------------
template <bool FUSE_POOL>
__global__ void gather_kernel(const float* __restrict__ xw, const float2* __restrict__ edat,
                              const int* __restrict__ ptr, const float* __restrict__ dinv,
                              const float* __restrict__ b, const int* __restrict__ batch,
                              float* __restrict__ out, float* __restrict__ sums,
                              float* __restrict__ gcnt, int N) {
    int tid = blockIdx.x * blockDim.x + threadIdx.x;
    if (tid >= N * DIM) return;
    int n = tid >> 5, d = tid & 31;
    int s = ptr[n], epos = ptr[n + 1];
    float di = dinv[n];
    float acc = xw[tid] * di * di + b[d];
    for (int e = s; e < epos; e++) {
        float2 ed = edat[e];  // broadcast across the 32 lanes of this node
        acc += ed.y * xw[__float_as_int(ed.x) * DIM + d];
    }
    if (FUSE_POOL) {
        int g = batch[n];
        atomicAdd(&sums[g * DIM + d], fmaxf(acc, 0.0f));
        if (d == 0) atomicAdd(&gcnt[g], 1.0f);
    } else {
        out[tid] = acc;
    }
}

// ---------------- post-MLP: relu(g@W0+b0) @ W1 + b1 -> sigmoid ----------------
__global__ void postmlp_kernel(const float* __restrict__ sums, const float* __restrict__ gcnt,
                               const float* __restrict__ W0, const float* __restrict__ b0,
                               const float* __restrict__ W1, const float* __restrict__ b1,
                               float* __restrict__ out, int G) {
    int g = blockIdx.x * blockDim.x + threadIdx.x;
    if (g >= G) return;
    float c = fmaxf(gcnt[g], 1.0f);
    float inv = 1.0f / c;
    float gv[DIM];
#pragma unroll
    for (int k = 0; k < DIM; k++) gv[k] = sums[g * DIM + k] * inv;
    float acc = b1[0];
#pragma unroll
    for (int j = 0; j < DIM; j++) {
        float p = b0[j];
#pragma unroll
        for (int k = 0; k < DIM; k++) p += gv[k] * W0[k * DIM + j];
        p = fmaxf(p, 0.0f);
        acc += p * W1[j];
    }
    out[g] = 1.0f / (1.0f + expf(-acc));
}

extern "C" void kernel_launch(void* const* d_in, const int* in_sizes, int n_in,
                              void* d_out, int out_size, void* d_ws, size_t ws_size,
                              hipStream_t stream) {
    const float* x   = (const float*)d_in[0];
    const int*   ei  = (const int*)d_in[1];
    const float* ew  = (const float*)d_in[2];
    const int*   bat = (const int*)d_in[3];
    const float* Wpre0 = (const float*)d_in[4];
    const float* bpre0 = (const float*)d_in[5];
    const float* Wpre1 = (const float*)d_in[6];
    const float* bpre1 = (const float*)d_in[7];
    const float* Wg[3]  = {(const float*)d_in[8],  (const float*)d_in[10], (const float*)d_in[12]};
    const float* bg[3]  = {(const float*)d_in[9],  (const float*)d_in[11], (const float*)d_in[13]};
    const float* Wpost0 = (const float*)d_in[14];
    const float* bpost0 = (const float*)d_in[15];
    const float* Wpost1 = (const float*)d_in[16];
    const float* bpost1 = (const float*)d_in[17];
    float* out = (float*)d_out;

    const int N = in_sizes[0];       // 160000
    const int E = in_sizes[2];       // 2560000
    const int G = out_size;          // 1024
    const int nb = (N + 255) / 256;  // scan blocks

    const int* row = ei;
    const int* col = ei + E;

    // ---- workspace layout (4-byte units) ----
    float* ws = (float*)d_ws;
    size_t nd = (size_t)N * DIM;
    float*  bufA  = ws;                          // nd   (h)
    float*  bufB  = bufA + nd;                   // nd   (xw)
    float*  dinv  = bufB + nd;                   // N    (deg -> dinv in place)
    int*    cnt   = (int*)(dinv + N);            // N    (counts -> cursor)
    float*  sums  = (float*)(cnt + N);           // G*DIM
    float*  gcnt  = sums + (size_t)G * DIM;      // G
    int*    ptr   = (int*)(gcnt + G);            // N+2 (pad to even)
    int*    bsum  = ptr + (N + 2);               // nb (pad to even)
    float2* edat  = (float2*)(bsum + ((nb + 1) & ~1)); // E * 8B

    // zero the atomic accumulators: dinv(deg) | cnt | sums | gcnt  (contiguous)
    hipMemsetAsync(dinv, 0, sizeof(float) * ((size_t)N + N + (size_t)G * DIM + G), stream);

    const int B = 256;
    int ndThreads = N * DIM;

    // degree + count
    deg_cnt_kernel<<<(E + B - 1) / B, B, 0, stream>>>(col, ew, dinv, cnt, E);
    dinv_kernel<<<(N + B - 1) / B, B, 0, stream>>>(dinv, N);

    // CSR build: scan + sort (norm precomputed once)
    scan_block_kernel<<<nb, 256, 0, stream>>>(cnt, ptr, bsum, N);
    scan_tops_kernel<<<1, 64, 0, stream>>>(bsum, ptr, nb, N);
    scan_add_kernel<<<(N + B - 1) / B, B, 0, stream>>>(ptr, bsum, cnt, N);
    sort_kernel<<<(E + B - 1) / B, B, 0, stream>>>(row, col, ew, dinv, cnt, edat, E);

    // pre-MLP -> bufA
    premlp_kernel<<<(ndThreads + B - 1) / B, B, 0, stream>>>(x, Wpre0, bpre0, Wpre1, bpre1, bufA, N);

    // 3 GCN layers: xw: bufA->bufB ; gather: bufB->bufA (last fuses pool)
    for (int l = 0; l < 3; l++) {
        if (l == 0)
            xw_kernel<false><<<(ndThreads + B - 1) / B, B, 0, stream>>>(bufA, Wg[l], bufB, N);
        else
            xw_kernel<true><<<(ndThreads + B - 1) / B, B, 0, stream>>>(bufA, Wg[l], bufB, N);
        if (l < 2)
            gather_kernel<false><<<(ndThreads + B - 1) / B, B, 0, stream>>>(
                bufB, edat, ptr, dinv, bg[l], bat, bufA, sums, gcnt, N);
        else
            gather_kernel<true><<<(ndThreads + B - 1) / B, B, 0, stream>>>(
                bufB, edat, ptr, dinv, bg[l], bat, bufA, sums, gcnt, N);
    }

    // post-MLP
    postmlp_kernel<<<(G + B - 1) / B, B, 0, stream>>>(sums, gcnt, Wpost0, bpost0, Wpost1, bpost1, out, G);
}

// Round 3
// 982.912 us; speedup vs baseline: 1.3878x; 1.2925x over previous
//
#include <hip/hip_runtime.h>
#include <math.h>

#define DIM 32

// ---------------- degree (weighted) + in-degree count ----------------
__global__ void deg_cnt_kernel(const int* __restrict__ col, const float* __restrict__ w,
                               float* __restrict__ deg, int* __restrict__ cnt, int E) {
    int e = blockIdx.x * blockDim.x + threadIdx.x;
    if (e < E) {
        int c = col[e];
        atomicAdd(&deg[c], w[e]);
        atomicAdd(&cnt[c], 1);
    }
}

// dinv = rsqrt(deg+1), in place
__global__ void dinv_kernel(float* __restrict__ deg, int N) {
    int n = blockIdx.x * blockDim.x + threadIdx.x;
    if (n < N) deg[n] = rsqrtf(deg[n] + 1.0f);
}

// ---------------- scan: per-block exclusive scan of cnt -> ptr, block totals -> bsum ----------------
__global__ void scan_block_kernel(const int* __restrict__ cnt, int* __restrict__ ptr,
                                  int* __restrict__ bsum, int N) {
    __shared__ int s[256];
    int i = blockIdx.x * 256 + threadIdx.x;
    int v = (i < N) ? cnt[i] : 0;
    s[threadIdx.x] = v;
    __syncthreads();
#pragma unroll
    for (int off = 1; off < 256; off <<= 1) {
        int t = (threadIdx.x >= off) ? s[threadIdx.x - off] : 0;
        __syncthreads();
        s[threadIdx.x] += t;
        __syncthreads();
    }
    if (i < N) ptr[i] = s[threadIdx.x] - v;  // exclusive
    if (threadIdx.x == 255) bsum[blockIdx.x] = s[255];
}

// serial scan of block totals (nb=625, trivial)
__global__ void scan_tops_kernel(int* __restrict__ bsum, int* __restrict__ ptr, int nb, int N) {
    if (blockIdx.x == 0 && threadIdx.x == 0) {
        int run = 0;
        for (int b = 0; b < nb; b++) { int t = bsum[b]; bsum[b] = run; run += t; }
        ptr[N] = run;  // == E
    }
}

// add block offsets; also init cursor (reuses cnt buffer)
__global__ void scan_add_kernel(int* __restrict__ ptr, const int* __restrict__ bsum,
                                int* __restrict__ cursor, int N) {
    int i = blockIdx.x * blockDim.x + threadIdx.x;
    if (i < N) {
        int p = ptr[i] + bsum[i >> 8];
        ptr[i] = p;
        cursor[i] = p;
    }
}

// ---------------- counting-sort edges by col; precompute norm once ----------------
__global__ void sort_kernel(const int* __restrict__ row, const int* __restrict__ col,
                            const float* __restrict__ w, const float* __restrict__ dinv,
                            int* __restrict__ cursor, float2* __restrict__ edat, int E) {
    int e = blockIdx.x * blockDim.x + threadIdx.x;
    if (e >= E) return;
    int r = row[e], c = col[e];
    float nm = dinv[r] * w[e] * dinv[c];
    int pos = atomicAdd(&cursor[c], 1);
    edat[pos] = make_float2(__int_as_float(r), nm);
}

// ---------------- pre-MLP (2 layers) + xw0 = h @ Wg0, fused via shuffle matmul ----------------
__global__ void premlp_xw_kernel(const float* __restrict__ x,
                                 const float* __restrict__ W0, const float* __restrict__ b0,
                                 const float* __restrict__ W1, const float* __restrict__ b1,
                                 const float* __restrict__ Wg, float* __restrict__ xw0, int N) {
    int tid = blockIdx.x * blockDim.x + threadIdx.x;
    if (tid >= N * DIM) return;
    int n = tid >> 5, d = tid & 31;
    float xv = x[n];
    float acc = b1[d];
#pragma unroll
    for (int k = 0; k < DIM; k++) {
        float h0 = fmaxf(xv * W0[k] + b0[k], 0.0f);
        acc += h0 * W1[k * DIM + d];
    }
    float h = fmaxf(acc, 0.0f);
    float o = 0.0f;
#pragma unroll
    for (int k = 0; k < DIM; k++) {
        float hk = __shfl(h, k, 32);
        o += hk * Wg[k * DIM + d];
    }
    xw0[tid] = o;
}

// ---------------- fused CSR gather + (next-xw | pool) ----------------
// agg = b[d] + xw[n]*dinv^2 + sum_e norm*xw[row];  h = relu(agg)
// FUSE_POOL=false: out = h @ Wn (shuffle matmul)   FUSE_POOL=true: pool atomics
template <bool FUSE_POOL>
__global__ void gather_kernel(const float* __restrict__ xw, const float2* __restrict__ edat,
                              const int* __restrict__ ptr, const float* __restrict__ dinv,
                              const float* __restrict__ b, const float* __restrict__ Wn,
                              const int* __restrict__ batch,
                              float* __restrict__ out, float* __restrict__ sums,
                              float* __restrict__ gcnt, int N) {
    int tid = blockIdx.x * blockDim.x + threadIdx.x;
    if (tid >= N * DIM) return;
    int n = tid >> 5, d = tid & 31;
    int s = ptr[n], epos = ptr[n + 1];
    float di = dinv[n];
    float acc = xw[tid] * di * di + b[d];
    for (int base = s; base < epos; base += 32) {
        int idx = base + d;  // lane-cooperative coalesced load of 32 edges
        float2 ed = (idx < epos) ? edat[idx] : make_float2(__int_as_float(0), 0.0f);
        int ri = __float_as_int(ed.x);
#pragma unroll
        for (int j = 0; j < 32; j++) {
            int r = __shfl(ri, j, 32);
            float nm = __shfl(ed.y, j, 32);
            acc += nm * xw[r * DIM + d];  // 32 independent gathers in flight
        }
    }
    float h = fmaxf(acc, 0.0f);
    if (FUSE_POOL) {
        int g = batch[n];
        atomicAdd(&sums[g * DIM + d], h);
        if (d == 0) atomicAdd(&gcnt[g], 1.0f);
    } else {
        float o = 0.0f;
#pragma unroll
        for (int k = 0; k < DIM; k++) {
            float hk = __shfl(h, k, 32);
            o += hk * Wn[k * DIM + d];
        }
        out[tid] = o;
    }
}

// ---------------- post-MLP: relu(g@W0+b0) @ W1 + b1 -> sigmoid ----------------
__global__ void postmlp_kernel(const float* __restrict__ sums, const float* __restrict__ gcnt,
                               const float* __restrict__ W0, const float* __restrict__ b0,
                               const float* __restrict__ W1, const float* __restrict__ b1,
                               float* __restrict__ out, int G) {
    int g = blockIdx.x * blockDim.x + threadIdx.x;
    if (g >= G) return;
    float c = fmaxf(gcnt[g], 1.0f);
    float inv = 1.0f / c;
    float gv[DIM];
#pragma unroll
    for (int k = 0; k < DIM; k++) gv[k] = sums[g * DIM + k] * inv;
    float acc = b1[0];
#pragma unroll
    for (int j = 0; j < DIM; j++) {
        float p = b0[j];
#pragma unroll
        for (int k = 0; k < DIM; k++) p += gv[k] * W0[k * DIM + j];
        p = fmaxf(p, 0.0f);
        acc += p * W1[j];
    }
    out[g] = 1.0f / (1.0f + expf(-acc));
}

extern "C" void kernel_launch(void* const* d_in, const int* in_sizes, int n_in,
                              void* d_out, int out_size, void* d_ws, size_t ws_size,
                              hipStream_t stream) {
    const float* x   = (const float*)d_in[0];
    const int*   ei  = (const int*)d_in[1];
    const float* ew  = (const float*)d_in[2];
    const int*   bat = (const int*)d_in[3];
    const float* Wpre0 = (const float*)d_in[4];
    const float* bpre0 = (const float*)d_in[5];
    const float* Wpre1 = (const float*)d_in[6];
    const float* bpre1 = (const float*)d_in[7];
    const float* Wg[3]  = {(const float*)d_in[8],  (const float*)d_in[10], (const float*)d_in[12]};
    const float* bg[3]  = {(const float*)d_in[9],  (const float*)d_in[11], (const float*)d_in[13]};
    const float* Wpost0 = (const float*)d_in[14];
    const float* bpost0 = (const float*)d_in[15];
    const float* Wpost1 = (const float*)d_in[16];
    const float* bpost1 = (const float*)d_in[17];
    float* out = (float*)d_out;

    const int N = in_sizes[0];       // 160000
    const int E = in_sizes[2];       // 2560000
    const int G = out_size;          // 1024
    const int nb = (N + 255) / 256;  // scan blocks

    const int* row = ei;
    const int* col = ei + E;

    // ---- workspace layout (4-byte units) ----
    float* ws = (float*)d_ws;
    size_t nd = (size_t)N * DIM;
    float*  bufA  = ws;                          // nd
    float*  bufB  = bufA + nd;                   // nd
    float*  dinv  = bufB + nd;                   // N    (deg -> dinv in place)
    int*    cnt   = (int*)(dinv + N);            // N    (counts -> cursor)
    float*  sums  = (float*)(cnt + N);           // G*DIM
    float*  gcnt  = sums + (size_t)G * DIM;      // G
    int*    ptr   = (int*)(gcnt + G);            // N+2 (pad to even)
    int*    bsum  = ptr + (N + 2);               // nb (pad to even)
    float2* edat  = (float2*)(bsum + ((nb + 1) & ~1)); // E * 8B

    // zero the atomic accumulators: dinv(deg) | cnt | sums | gcnt  (contiguous)
    hipMemsetAsync(dinv, 0, sizeof(float) * ((size_t)N + N + (size_t)G * DIM + G), stream);

    const int B = 256;
    int ndThreads = N * DIM;

    // degree + count
    deg_cnt_kernel<<<(E + B - 1) / B, B, 0, stream>>>(col, ew, dinv, cnt, E);
    dinv_kernel<<<(N + B - 1) / B, B, 0, stream>>>(dinv, N);

    // CSR build: scan + sort (norm precomputed once)
    scan_block_kernel<<<nb, 256, 0, stream>>>(cnt, ptr, bsum, N);
    scan_tops_kernel<<<1, 64, 0, stream>>>(bsum, ptr, nb, N);
    scan_add_kernel<<<(N + B - 1) / B, B, 0, stream>>>(ptr, bsum, cnt, N);
    sort_kernel<<<(E + B - 1) / B, B, 0, stream>>>(row, col, ew, dinv, cnt, edat, E);

    // pre-MLP + xw0 -> bufB
    premlp_xw_kernel<<<(ndThreads + B - 1) / B, B, 0, stream>>>(
        x, Wpre0, bpre0, Wpre1, bpre1, Wg[0], bufB, N);

    // L0: gather(xw0) + xw1  : bufB -> bufA   (uses bg[0], Wg[1])
    gather_kernel<false><<<(ndThreads + B - 1) / B, B, 0, stream>>>(
        bufB, edat, ptr, dinv, bg[0], Wg[1], bat, bufA, sums, gcnt, N);
    // L1: gather(xw1) + xw2  : bufA -> bufB   (uses bg[1], Wg[2])
    gather_kernel<false><<<(ndThreads + B - 1) / B, B, 0, stream>>>(
        bufA, edat, ptr, dinv, bg[1], Wg[2], bat, bufB, sums, gcnt, N);
    // L2: gather(xw2) + pool (uses bg[2])
    gather_kernel<true><<<(ndThreads + B - 1) / B, B, 0, stream>>>(
        bufB, edat, ptr, dinv, bg[2], nullptr, bat, nullptr, sums, gcnt, N);

    // post-MLP
    postmlp_kernel<<<(G + B - 1) / B, B, 0, stream>>>(sums, gcnt, Wpost0, bpost0, Wpost1, bpost1, out, G);
}